// Round 2
// baseline (800.250 us; speedup 1.0000x reference)
//
#include <hip/hip_runtime.h>

// Problem constants
#define BQ      8
#define SEQ     4096
#define DIM_    1024
#define QKVD    3072
#define NPATCH  206     // patch rows; token t = 40*(r>>1) + 2*s + (r&1), s in [0,20)
#define MTOT    (BQ * SEQ)   // 32768 real tokens (pad tokens have qkv == 0, never materialized)

typedef __bf16 bf16x8 __attribute__((ext_vector_type(8)));
typedef float  f32x4  __attribute__((ext_vector_type(4)));

__device__ __forceinline__ float bf2f(unsigned int u16) {
  union { unsigned int i; float f; } x;
  x.i = u16 << 16;
  return x.f;
}
__device__ __forceinline__ unsigned short f2bf(float f) {
  union { float f; unsigned int i; } x; x.f = f;
  unsigned int r = x.i + 0x7fffu + ((x.i >> 16) & 1u);  // RNE
  return (unsigned short)(r >> 16);
}

__device__ __forceinline__ void load_lds16(const void* g, void* l) {
  __builtin_amdgcn_global_load_lds(
      (const __attribute__((address_space(1))) void*)g,
      (__attribute__((address_space(3))) void*)l, 16, 0, 0);
}

// fp32 -> bf16 (RNE) conversion for x, Wqkv, Wout in one pass.
__global__ __launch_bounds__(256) void cvt_kernel(
    const float* __restrict__ x,  unsigned short* __restrict__ xb,
    const float* __restrict__ w1, unsigned short* __restrict__ w1b,
    const float* __restrict__ w2, unsigned short* __restrict__ w2b)
{
  const long long NX = (long long)MTOT * DIM_;   // 33,554,432
  const long long NW1 = (long long)QKVD * DIM_;  //  3,145,728
  const long long NW2 = (long long)DIM_ * DIM_;  //  1,048,576
  const long long total4 = (NX + NW1 + NW2) >> 2;
  for (long long q = (long long)blockIdx.x * 256 + threadIdx.x; q < total4;
       q += (long long)gridDim.x * 256) {
    const float* src; unsigned short* dst; long long i;
    if (q < (NX >> 2))              { src = x;  dst = xb;  i = (q << 2); }
    else if (q < ((NX + NW1) >> 2)) { src = w1; dst = w1b; i = (q << 2) - NX; }
    else                            { src = w2; dst = w2b; i = (q << 2) - NX - NW1; }
    float4 v = *(const float4*)(src + i);
    ushort4 o;
    o.x = f2bf(v.x); o.y = f2bf(v.y); o.z = f2bf(v.z); o.w = f2bf(v.w);
    *(ushort4*)(dst + i) = o;
  }
}

// C[M,N] = A[M,K] * B[N,K]^T (+bias), bf16 in, fp32 accum, bf16 or fp32 out.
// Block: 256 threads = 4 waves, 128x128 C-tile, BK=32, m97-style structure.
template <bool HAS_BIAS, bool OUT_F32>
__global__ __launch_bounds__(256) void gemm_bt(
    const unsigned short* __restrict__ A,
    const unsigned short* __restrict__ Bm,
    const float* __restrict__ bias,     // fp32 bias (final GEMM only)
    void* __restrict__ Cv,
    int N, int K)
{
  __shared__ alignas(16) unsigned short As[128 * 32];
  __shared__ alignas(16) unsigned short Bs[128 * 32];

  const int tid  = threadIdx.x;
  const size_t bm = (size_t)blockIdx.y * 128;
  const size_t bn = (size_t)blockIdx.x * 128;
  const int wave = tid >> 6;
  const int lane = tid & 63;
  const int wm = (wave >> 1) * 64;
  const int wn = (wave & 1) * 64;
  const int fr = lane & 15;         // fragment row (m for A, n for B)
  const int fk = (lane >> 4) * 8;   // fragment k offset

  f32x4 acc[4][4];
#pragma unroll
  for (int i = 0; i < 4; ++i)
#pragma unroll
    for (int j = 0; j < 4; ++j)
      acc[i][j] = (f32x4){0.f, 0.f, 0.f, 0.f};

  // staging: 128x32 tile, flat row-major in LDS (global_load_lds is
  // wave-uniform base + lane*16 -> As[tid*8] == row tid/4, col (tid&3)*8)
  const int srow = tid >> 2;
  const int scol = (tid & 3) * 8;
  const unsigned short* gA0 = A  + (bm + srow) * (size_t)K + scol;
  const unsigned short* gA1 = A  + (bm + 64 + srow) * (size_t)K + scol;
  const unsigned short* gB0 = Bm + (bn + srow) * (size_t)K + scol;
  const unsigned short* gB1 = Bm + (bn + 64 + srow) * (size_t)K + scol;
  unsigned short* lA0 = &As[tid * 8];
  unsigned short* lA1 = &As[2048 + tid * 8];
  unsigned short* lB0 = &Bs[tid * 8];
  unsigned short* lB1 = &Bs[2048 + tid * 8];

  for (int kt = 0; kt < K; kt += 32) {
    load_lds16(gA0 + kt, lA0);
    load_lds16(gA1 + kt, lA1);
    load_lds16(gB0 + kt, lB0);
    load_lds16(gB1 + kt, lB1);
    __syncthreads();

    bf16x8 af[4], bfm[4];
#pragma unroll
    for (int i = 0; i < 4; ++i)
      af[i] = *(const bf16x8*)(&As[(wm + i * 16 + fr) * 32 + fk]);
#pragma unroll
    for (int j = 0; j < 4; ++j)
      bfm[j] = *(const bf16x8*)(&Bs[(wn + j * 16 + fr) * 32 + fk]);
#pragma unroll
    for (int i = 0; i < 4; ++i)
#pragma unroll
      for (int j = 0; j < 4; ++j)
        acc[i][j] = __builtin_amdgcn_mfma_f32_16x16x32_bf16(af[i], bfm[j], acc[i][j], 0, 0, 0);
    __syncthreads();
  }

  // Epilogue: C/D layout col = lane&15, row = (lane>>4)*4 + reg  [m89/m91 verified]
  const int crow0 = (lane >> 4) * 4;
  const int ccol  = lane & 15;
  float bv[4];
  if (HAS_BIAS) {
#pragma unroll
    for (int j = 0; j < 4; ++j) bv[j] = bias[bn + wn + j * 16 + ccol];
  }
#pragma unroll
  for (int i = 0; i < 4; ++i) {
#pragma unroll
    for (int j = 0; j < 4; ++j) {
      size_t base = (bm + wm + i * 16 + crow0) * (size_t)N + (bn + wn + j * 16 + ccol);
#pragma unroll
      for (int r2 = 0; r2 < 4; ++r2) {
        float v = acc[i][j][r2];
        if (HAS_BIAS) v += bv[j];
        if (OUT_F32) ((float*)Cv)[base + (size_t)r2 * N] = v;
        else ((unsigned short*)Cv)[base + (size_t)r2 * N] = f2bf(v);
      }
    }
  }
}

// Per-patch attention. Block = (patch r, head-half, batch), 256 threads.
// qkv: [B*SEQ][3072] bf16 (q: h*64, k: 1024+h*64, v: 2048+h*64).
// y:   [B*SEQ][1024] bf16 (attention outputs scattered back to token order).
// Pad tokens (t>=4096): k=v=0 (zero-filled LDS) -> logits vs pad keys are 0
// and participate in softmax, matching the reference. Pad-query rows skipped.
#define KV_STRIDE 520  // 512 elems + 8 pad
__global__ __launch_bounds__(256) void attn_kernel(
    const unsigned short* __restrict__ qkv,
    unsigned short* __restrict__ y)
{
  const int r    = blockIdx.x;   // 0..205
  const int half = blockIdx.y;   // 0..1 (8 heads each)
  const int b    = blockIdx.z;   // 0..7
  const int tid  = threadIdx.x;
  const int tbase = 40 * (r >> 1) + (r & 1);
  const int hq_off = half * 512;

  __shared__ alignas(16) unsigned short Ks[20 * KV_STRIDE];
  __shared__ alignas(16) unsigned short Vs[20 * KV_STRIDE];
  __shared__ float L[8 * 20 * 20];   // logits -> softmax weights

  // ---- stage K,V for this half's 8 heads: 20 tokens x 512 dims each ----
  for (int c = tid; c < 2560; c += 256) {
    int tok = c >> 7;
    int kv  = (c >> 6) & 1;
    int j   = c & 63;
    int t   = tbase + 2 * tok;
    int4 data;
    if (t < SEQ) {
      const unsigned short* src = qkv + ((size_t)(b * SEQ + t)) * QKVD
                                  + 1024 + kv * 1024 + hq_off + j * 8;
      data = *(const int4*)src;
    } else {
      data = make_int4(0, 0, 0, 0);
    }
    unsigned short* dst = (kv ? Vs : Ks) + tok * KV_STRIDE + j * 8;
    *(int4*)dst = data;
  }
  __syncthreads();

  // ---- logits: 8 heads x 20 s x 20 u = 3200 dots of length 64 ----
  for (int i = tid; i < 3200; i += 256) {
    int h   = i / 400;
    int rem = i - h * 400;
    int s   = rem / 20;
    int u   = rem - s * 20;
    int tq  = tbase + 2 * s;
    float dot = 0.f;
    if (tq < SEQ) {
      const unsigned int* q32 = (const unsigned int*)(qkv + (size_t)(b * SEQ + tq) * QKVD + hq_off + h * 64);
      const unsigned int* k32 = (const unsigned int*)(Ks + u * KV_STRIDE + h * 64);
#pragma unroll
      for (int e2 = 0; e2 < 32; ++e2) {
        unsigned int qa = q32[e2], ka = k32[e2];
        dot += bf2f(qa & 0xffffu) * bf2f(ka & 0xffffu);
        dot += bf2f(qa >> 16)     * bf2f(ka >> 16);
      }
    }
    L[(h * 20 + s) * 20 + u] = dot * 0.125f;   // scale = 64^-0.5
  }
  __syncthreads();

  // ---- softmax over 20 keys, one thread per (h, s) row ----
  if (tid < 160) {
    int h = tid / 20;
    int s = tid - h * 20;
    float* row = &L[(h * 20 + s) * 20];
    float m = -1e30f;
#pragma unroll
    for (int u = 0; u < 20; ++u) m = fmaxf(m, row[u]);
    float w[20];
    float sum = 0.f;
#pragma unroll
    for (int u = 0; u < 20; ++u) { w[u] = __expf(row[u] - m); sum += w[u]; }
    float inv = 1.f / sum;
#pragma unroll
    for (int u = 0; u < 20; ++u) row[u] = w[u] * inv;
  }
  __syncthreads();

  // ---- PV: out[h][s][e] = sum_u w[h][s][u] * V[u][h*64+e]; scatter to y ----
  for (int i = tid; i < 10240; i += 256) {
    int e    = i & 63;
    int rest = i >> 6;        // 0..159
    int s    = rest % 20;
    int h    = rest / 20;
    int tq   = tbase + 2 * s;
    if (tq >= SEQ) continue;
    const float* w = &L[(h * 20 + s) * 20];
    const unsigned short* vp = Vs + h * 64 + e;
    float acc = 0.f;
#pragma unroll
    for (int u = 0; u < 20; ++u)
      acc += w[u] * bf2f(vp[u * KV_STRIDE]);
    y[(size_t)(b * SEQ + tq) * DIM_ + hq_off + h * 64 + e] = f2bf(acc);
  }
}

extern "C" void kernel_launch(void* const* d_in, const int* in_sizes, int n_in,
                              void* d_out, int out_size, void* d_ws, size_t ws_size,
                              hipStream_t stream) {
  const float* x    = (const float*)d_in[0];  // [8,4096,1024] fp32
  const float* Wqkv = (const float*)d_in[1];  // [3072,1024]  fp32
  const float* Wout = (const float*)d_in[2];  // [1024,1024]  fp32
  const float* bout = (const float*)d_in[3];  // [1024]       fp32
  float* out = (float*)d_out;                 // [8,4096,1024] fp32

  // ws layout (bytes):
  //   xb_y  : 67,108,864  (x as bf16 for GEMM-1; reused as y after GEMM-1)
  //   wqkvb :  6,291,456
  //   woutb :  2,097,152
  //   qkv   : 201,326,592
  // total ~277 MB
  unsigned short* xb_y  = (unsigned short*)d_ws;
  unsigned short* wqkvb = xb_y  + (size_t)MTOT * DIM_;
  unsigned short* woutb = wqkvb + (size_t)QKVD * DIM_;
  unsigned short* qkv   = woutb + (size_t)DIM_ * DIM_;

  // 0) fp32 -> bf16 conversions
  cvt_kernel<<<2048, 256, 0, stream>>>(x, xb_y, Wqkv, wqkvb, Wout, woutb);

  // 1) qkv = x @ Wqkv^T   (M=32768, N=3072, K=1024), bf16 out
  gemm_bt<false, false><<<dim3(QKVD / 128, MTOT / 128), 256, 0, stream>>>(
      xb_y, wqkvb, nullptr, qkv, QKVD, DIM_);

  // 2) per-patch attention, scatter back to token order (y overwrites xb)
  attn_kernel<<<dim3(NPATCH, 2, BQ), 256, 0, stream>>>(qkv, xb_y);

  // 3) out = y @ Wout^T + bout   (M=32768, N=1024, K=1024), fp32 out
  gemm_bt<true, true><<<dim3(DIM_ / 128, MTOT / 128), 256, 0, stream>>>(
      xb_y, woutb, bout, out, DIM_, DIM_);
}

// Round 3
// 758.274 us; speedup vs baseline: 1.0554x; 1.0554x over previous
//
#include <hip/hip_runtime.h>

// Problem constants
#define BQ      8
#define SEQ     4096
#define DIM_    1024
#define QKVD    3072
#define NPATCH  206     // patch rows; token t = 40*(r>>1) + 2*s + (r&1), s in [0,20)
#define MTOT    (BQ * SEQ)

typedef __bf16 bf16x8 __attribute__((ext_vector_type(8)));
typedef float  f32x4  __attribute__((ext_vector_type(4)));

__device__ __forceinline__ float bf2f(unsigned int u16) {
  union { unsigned int i; float f; } x;
  x.i = u16 << 16;
  return x.f;
}
__device__ __forceinline__ unsigned short f2bf(float f) {
  union { float f; unsigned int i; } x; x.f = f;
  unsigned int r = x.i + 0x7fffu + ((x.i >> 16) & 1u);  // RNE
  return (unsigned short)(r >> 16);
}

__device__ __forceinline__ void load_lds16(const void* g, void* l) {
  __builtin_amdgcn_global_load_lds(
      (const __attribute__((address_space(1))) void*)g,
      (__attribute__((address_space(3))) void*)l, 16, 0, 0);
}

// fp32 -> bf16 (RNE) conversion for x, Wqkv, Wout in one pass.
__global__ __launch_bounds__(256) void cvt_kernel(
    const float* __restrict__ x,  unsigned short* __restrict__ xb,
    const float* __restrict__ w1, unsigned short* __restrict__ w1b,
    const float* __restrict__ w2, unsigned short* __restrict__ w2b)
{
  const long long NX  = (long long)MTOT * DIM_;
  const long long NW1 = (long long)QKVD * DIM_;
  const long long NW2 = (long long)DIM_ * DIM_;
  const long long total4 = (NX + NW1 + NW2) >> 2;
  for (long long q = (long long)blockIdx.x * 256 + threadIdx.x; q < total4;
       q += (long long)gridDim.x * 256) {
    const float* src; unsigned short* dst; long long i;
    if (q < (NX >> 2))              { src = x;  dst = xb;  i = (q << 2); }
    else if (q < ((NX + NW1) >> 2)) { src = w1; dst = w1b; i = (q << 2) - NX; }
    else                            { src = w2; dst = w2b; i = (q << 2) - NX - NW1; }
    float4 v = *(const float4*)(src + i);
    ushort4 o;
    o.x = f2bf(v.x); o.y = f2bf(v.y); o.z = f2bf(v.z); o.w = f2bf(v.w);
    *(ushort4*)(dst + i) = o;
  }
}

// C[M,N] = A[M,K] * B[N,K]^T (+bias), bf16 in, fp32 accum, bf16/fp32 out.
// 256 threads = 4 waves, 128x128 C-tile, BK=32.
// LDS chunk layout XOR-swizzled: chunk (row r, c) lives at slot
// (r>>4)*64 + (r&15)*4 + (c ^ ((r>>1)&3)).  Staging picks the matching
// global source per lane (LDS side of global_load_lds is fixed base+lane*16);
// fragment reads then hit all 8 bank-groups 2x per quarter-wave (conflict-free
// per m136: 2-way is free; previous flat layout was 8-way = 2.9x).
template <bool HAS_BIAS, bool OUT_F32>
__global__ __launch_bounds__(256) void gemm_bt(
    const unsigned short* __restrict__ A,
    const unsigned short* __restrict__ Bm,
    const float* __restrict__ bias,
    void* __restrict__ Cv,
    int N, int K)
{
  __shared__ alignas(16) unsigned short As[128 * 32];
  __shared__ alignas(16) unsigned short Bs[128 * 32];

  const int tid  = threadIdx.x;
  const size_t bm = (size_t)blockIdx.y * 128;
  const size_t bn = (size_t)blockIdx.x * 128;
  const int wave = tid >> 6;
  const int lane = tid & 63;
  const int wm = (wave >> 1) * 64;
  const int wn = (wave & 1) * 64;
  const int fr = lane & 15;       // fragment row (m for A, n for B)
  const int fq = lane >> 4;       // k-chunk index 0..3 (k offset = fq*8)

  f32x4 acc[4][4];
#pragma unroll
  for (int i = 0; i < 4; ++i)
#pragma unroll
    for (int j = 0; j < 4; ++j)
      acc[i][j] = (f32x4){0.f, 0.f, 0.f, 0.f};

  // staging with XOR-swizzled source chunk
  const int srow  = tid >> 2;
  const int c_src = (tid & 3) ^ ((tid >> 3) & 3);
  const int scol  = c_src * 8;
  const unsigned short* gA0 = A  + (bm + srow) * (size_t)K + scol;
  const unsigned short* gA1 = A  + (bm + 64 + srow) * (size_t)K + scol;
  const unsigned short* gB0 = Bm + (bn + srow) * (size_t)K + scol;
  const unsigned short* gB1 = Bm + (bn + 64 + srow) * (size_t)K + scol;
  unsigned short* lA0 = &As[tid * 8];
  unsigned short* lA1 = &As[2048 + tid * 8];
  unsigned short* lB0 = &Bs[tid * 8];
  unsigned short* lB1 = &Bs[2048 + tid * 8];

  // fragment-read offset within each 512-elem (16-row) group
  const int frx = fr * 32 + ((fq ^ ((fr >> 1) & 3)) * 8);
  const int ga0 = ((wm >> 4) + 0) * 512 + frx;
  const int gb0 = ((wn >> 4) + 0) * 512 + frx;

  for (int kt = 0; kt < K; kt += 32) {
    load_lds16(gA0 + kt, lA0);
    load_lds16(gA1 + kt, lA1);
    load_lds16(gB0 + kt, lB0);
    load_lds16(gB1 + kt, lB1);
    __syncthreads();

    bf16x8 af[4], bfm[4];
#pragma unroll
    for (int i = 0; i < 4; ++i)
      af[i] = *(const bf16x8*)(&As[ga0 + i * 512]);
#pragma unroll
    for (int j = 0; j < 4; ++j)
      bfm[j] = *(const bf16x8*)(&Bs[gb0 + j * 512]);
#pragma unroll
    for (int i = 0; i < 4; ++i)
#pragma unroll
      for (int j = 0; j < 4; ++j)
        acc[i][j] = __builtin_amdgcn_mfma_f32_16x16x32_bf16(af[i], bfm[j], acc[i][j], 0, 0, 0);
    __syncthreads();
  }

  // Epilogue: C/D layout col = lane&15, row = (lane>>4)*4 + reg  [m89/m91]
  const int crow0 = (lane >> 4) * 4;
  const int ccol  = lane & 15;
  float bv[4];
  if (HAS_BIAS) {
#pragma unroll
    for (int j = 0; j < 4; ++j) bv[j] = bias[bn + wn + j * 16 + ccol];
  }
#pragma unroll
  for (int i = 0; i < 4; ++i) {
#pragma unroll
    for (int j = 0; j < 4; ++j) {
      size_t base = (bm + wm + i * 16 + crow0) * (size_t)N + (bn + wn + j * 16 + ccol);
#pragma unroll
      for (int r2 = 0; r2 < 4; ++r2) {
        float v = acc[i][j][r2];
        if (HAS_BIAS) v += bv[j];
        if (OUT_F32) ((float*)Cv)[base + (size_t)r2 * N] = v;
        else ((unsigned short*)Cv)[base + (size_t)r2 * N] = f2bf(v);
      }
    }
  }
}

// Per-patch attention. Block = (patch r, head-half, batch), 256 threads.
// K staged as fp32 in LDS (decoded once), V as bf16; logits read K via
// ds_read_b128, PV vectorized over 4-elem chunks. Pad tokens -> K=V=0,
// logits 0 participate in softmax (matches reference); pad queries skipped.
#define KSF 516   // float stride per token (512 + 4)
#define VST 520   // ushort stride per token (512 + 8)
__global__ __launch_bounds__(256) void attn_kernel(
    const unsigned short* __restrict__ qkv,
    unsigned short* __restrict__ y)
{
  const int r    = blockIdx.x;   // 0..205
  const int half = blockIdx.y;   // 0..1
  const int b    = blockIdx.z;   // 0..7
  const int tid  = threadIdx.x;
  const int tbase = 40 * (r >> 1) + (r & 1);
  const int hq_off = half * 512;

  __shared__ alignas(16) float Ksf[20 * KSF];            // 41280 B
  __shared__ alignas(16) unsigned short Vs[20 * VST];    // 20800 B
  __shared__ float L[8 * 20 * 20];                       // 12800 B

  // ---- stage: 20 tokens x (K 512 + V 512), 8-elem items ----
  for (int c = tid; c < 2560; c += 256) {
    int tok = c >> 7;
    int kv  = (c >> 6) & 1;
    int j   = c & 63;
    int t   = tbase + 2 * tok;
    int4 data;
    if (t < SEQ) {
      const unsigned short* src = qkv + ((size_t)(b * SEQ + t)) * QKVD
                                  + 1024 + kv * 1024 + hq_off + j * 8;
      data = *(const int4*)src;
    } else {
      data = make_int4(0, 0, 0, 0);
    }
    if (kv == 0) {
      const unsigned short* u = (const unsigned short*)&data;
      float4 f0, f1;
      f0.x = bf2f(u[0]); f0.y = bf2f(u[1]); f0.z = bf2f(u[2]); f0.w = bf2f(u[3]);
      f1.x = bf2f(u[4]); f1.y = bf2f(u[5]); f1.z = bf2f(u[6]); f1.w = bf2f(u[7]);
      *(float4*)(&Ksf[tok * KSF + j * 8])     = f0;
      *(float4*)(&Ksf[tok * KSF + j * 8 + 4]) = f1;
    } else {
      *(int4*)(&Vs[tok * VST + j * 8]) = data;
    }
  }
  __syncthreads();

  // ---- logits: 8h x 20s x 20u dots of length 64 ----
  for (int i = tid; i < 3200; i += 256) {
    int h   = i / 400;
    int rem = i - h * 400;
    int s   = rem / 20;
    int u   = rem - s * 20;
    int tq  = tbase + 2 * s;
    float dot = 0.f;
    if (tq < SEQ) {
      const int2* q64 = (const int2*)(qkv + (size_t)(b * SEQ + tq) * QKVD + hq_off + h * 64);
      const f32x4* kf = (const f32x4*)(&Ksf[u * KSF + h * 64]);
#pragma unroll
      for (int e4 = 0; e4 < 16; ++e4) {
        int2 qa = q64[e4];
        f32x4 kv4 = kf[e4];
        dot += bf2f((unsigned int)qa.x & 0xffffu) * kv4.x
             + bf2f((unsigned int)qa.x >> 16)     * kv4.y
             + bf2f((unsigned int)qa.y & 0xffffu) * kv4.z
             + bf2f((unsigned int)qa.y >> 16)     * kv4.w;
      }
    }
    L[(h * 20 + s) * 20 + u] = dot * 0.125f;
  }
  __syncthreads();

  // ---- softmax over 20 keys, one thread per (h, s) ----
  if (tid < 160) {
    int h = tid / 20;
    int s = tid - h * 20;
    float* row = &L[(h * 20 + s) * 20];
    float m = -1e30f;
#pragma unroll
    for (int u = 0; u < 20; ++u) m = fmaxf(m, row[u]);
    float w[20];
    float sum = 0.f;
#pragma unroll
    for (int u = 0; u < 20; ++u) { w[u] = __expf(row[u] - m); sum += w[u]; }
    float inv = 1.f / sum;
#pragma unroll
    for (int u = 0; u < 20; ++u) row[u] = w[u] * inv;
  }
  __syncthreads();

  // ---- PV: 8h x 20s x 16 e4-chunks; ushort4 stores ----
  for (int i = tid; i < 2560; i += 256) {
    int e4   = i & 15;
    int rest = i >> 4;
    int s    = rest % 20;
    int h    = rest / 20;
    int tq   = tbase + 2 * s;
    if (tq >= SEQ) continue;
    const float* w = &L[(h * 20 + s) * 20];
    const unsigned short* vp = Vs + h * 64 + e4 * 4;
    float a0 = 0.f, a1 = 0.f, a2 = 0.f, a3 = 0.f;
#pragma unroll
    for (int u = 0; u < 20; ++u) {
      float wu = w[u];
      uint2 vv = *(const uint2*)(vp + u * VST);
      a0 += wu * bf2f(vv.x & 0xffffu);
      a1 += wu * bf2f(vv.x >> 16);
      a2 += wu * bf2f(vv.y & 0xffffu);
      a3 += wu * bf2f(vv.y >> 16);
    }
    ushort4 o;
    o.x = f2bf(a0); o.y = f2bf(a1); o.z = f2bf(a2); o.w = f2bf(a3);
    *(ushort4*)(&y[(size_t)(b * SEQ + tq) * DIM_ + hq_off + h * 64 + e4 * 4]) = o;
  }
}

extern "C" void kernel_launch(void* const* d_in, const int* in_sizes, int n_in,
                              void* d_out, int out_size, void* d_ws, size_t ws_size,
                              hipStream_t stream) {
  const float* x    = (const float*)d_in[0];  // [8,4096,1024] fp32
  const float* Wqkv = (const float*)d_in[1];  // [3072,1024]  fp32
  const float* Wout = (const float*)d_in[2];  // [1024,1024]  fp32
  const float* bout = (const float*)d_in[3];  // [1024]       fp32
  float* out = (float*)d_out;                 // [8,4096,1024] fp32

  unsigned short* xb_y  = (unsigned short*)d_ws;           // x bf16, reused as y
  unsigned short* wqkvb = xb_y  + (size_t)MTOT * DIM_;
  unsigned short* woutb = wqkvb + (size_t)QKVD * DIM_;
  unsigned short* qkv   = woutb + (size_t)DIM_ * DIM_;

  // 0) fp32 -> bf16
  cvt_kernel<<<2048, 256, 0, stream>>>(x, xb_y, Wqkv, wqkvb, Wout, woutb);

  // 1) qkv = x @ Wqkv^T   (M=32768, N=3072, K=1024), bf16 out
  gemm_bt<false, false><<<dim3(QKVD / 128, MTOT / 128), 256, 0, stream>>>(
      xb_y, wqkvb, nullptr, qkv, QKVD, DIM_);

  // 2) per-patch attention (y overwrites xb)
  attn_kernel<<<dim3(NPATCH, 2, BQ), 256, 0, stream>>>(qkv, xb_y);

  // 3) out = y @ Wout^T + bout   (M=32768, N=1024, K=1024), fp32 out
  gemm_bt<true, true><<<dim3(DIM_ / 128, MTOT / 128), 256, 0, stream>>>(
      xb_y, woutb, bout, out, DIM_, DIM_);
}